// Round 1
// baseline (585.025 us; speedup 1.0000x reference)
//
#include <hip/hip_runtime.h>

#define T_DIM 4096
#define B_DIM 4
#define NF 131
#define INV_SQRT_D 0.08838834764831845f
#define JITTER_F 1e-6f

typedef __bf16 bf16_t;
typedef bf16_t bf16x8 __attribute__((ext_vector_type(8)));
typedef bf16_t bf16x2 __attribute__((ext_vector_type(2)));
typedef float f32x4 __attribute__((ext_vector_type(4)));

// Kernel 1: per-row precompute.
// One wave per (b,t) row: mean copy, z -> bf16 (scaled by 1/sqrt(128)),
// h = 0.5*sum(z^2) (fp32), v, softplus(noise).
__global__ __launch_bounds__(256) void prep_kernel(
    const float* __restrict__ in, float* __restrict__ mean_out,
    bf16_t* __restrict__ Zb, float* __restrict__ h,
    float* __restrict__ v, float* __restrict__ noise) {
  const int row = blockIdx.x * 4 + (threadIdx.x >> 6);
  const int lane = threadIdx.x & 63;
  const float* x = in + (long)row * NF;
  float z0 = x[1 + lane * 2] * INV_SQRT_D;
  float z1 = x[2 + lane * 2] * INV_SQRT_D;
  bf16x2 p;
  p.x = (bf16_t)z0;
  p.y = (bf16_t)z1;
  *(bf16x2*)(Zb + (long)row * 128 + lane * 2) = p;
  float s = z0 * z0 + z1 * z1;
  #pragma unroll
  for (int m = 32; m > 0; m >>= 1) s += __shfl_down(s, m);
  if (lane == 0) {
    h[row] = 0.5f * s;
    mean_out[row] = x[0];
    v[row] = x[129];
    float t = x[130];
    noise[row] = (t > 15.0f) ? t : log1pf(__expf(t));
  }
}

// Kernel 2: 128x128 output tile per block. LDS-free, barrier-free.
// Swapped-operand MFMA (mfma(B,A) = G^T tile) puts 4 consecutive OUTPUT
// COLUMNS in each lane's f32x4 (i = l16 fixed, j = quad*4 + r), so the
// exp-epilogue runs in registers and stores directly as full-line float4
// NT stores (16 x 64B lines per wave store instruction).
// Fragments are loaded straight from L1/L2 (Zb = 4 MB, cache-resident);
// per load instruction the wave touches 16 x 64B lines -> fully coalesced.
// Epilogue params are loaded BEFORE any store so the vmcnt FIFO never
// forces a store drain to satisfy a load wait.
__global__ __launch_bounds__(256) void cov_kernel(
    const bf16_t* __restrict__ Zb, const float* __restrict__ h,
    const float* __restrict__ v, const float* __restrict__ noise,
    float* __restrict__ f_cov, float* __restrict__ y_cov) {
  const int jt = blockIdx.x, it = blockIdx.y, b = blockIdx.z;
  const int i0 = it * 128, j0 = jt * 128;
  const int tid = threadIdx.x;
  const int wave = tid >> 6, lane = tid & 63;
  const int wr = (wave >> 1) * 64, wc = (wave & 1) * 64;
  const int l16 = lane & 15, quad = lane >> 4;

  // This lane's row index base (i, fixed per mt-tile) and col base (j).
  const int ib = b * T_DIM + i0 + wr + l16;       // + mt*16
  const int jb = b * T_DIM + j0 + wc + quad * 4;  // + nt*16

  const bool diagblk = (it == jt);

  // ---- epilogue params first (early in vmcnt FIFO, L2-hot) ----
  float hA[4], vA[4], nA[4];
  f32x4 hB[4], vB[4];
  #pragma unroll
  for (int mt = 0; mt < 4; ++mt) {
    hA[mt] = h[ib + mt * 16];
    vA[mt] = v[ib + mt * 16];
    nA[mt] = diagblk ? noise[ib + mt * 16] : 0.0f;
  }
  #pragma unroll
  for (int nt = 0; nt < 4; ++nt) {
    hB[nt] = *(const f32x4*)(h + jb + nt * 16);
    vB[nt] = *(const f32x4*)(v + jb + nt * 16);
  }

  // ---- gram via MFMA, fragments direct from cache ----
  // A-slot operand rows = j (so D-row = j), B-slot operand cols = i (D-col = i).
  const bf16_t* Arow = Zb + ((long)ib << 7);                          // i rows
  const bf16_t* Brow = Zb + ((long)(b * T_DIM + j0 + wc + l16) << 7); // j rows

  f32x4 acc[4][4];
  #pragma unroll
  for (int mt = 0; mt < 4; ++mt)
    #pragma unroll
    for (int nt = 0; nt < 4; ++nt)
      acc[mt][nt] = (f32x4){0.f, 0.f, 0.f, 0.f};

  #pragma unroll
  for (int ks = 0; ks < 4; ++ks) {
    const int ko = ks * 32 + quad * 8;
    bf16x8 af[4], bfr[4];
    #pragma unroll
    for (int mt = 0; mt < 4; ++mt)
      af[mt] = *(const bf16x8*)(Arow + mt * 2048 + ko);
    #pragma unroll
    for (int nt = 0; nt < 4; ++nt)
      bfr[nt] = *(const bf16x8*)(Brow + nt * 2048 + ko);
    #pragma unroll
    for (int mt = 0; mt < 4; ++mt)
      #pragma unroll
      for (int nt = 0; nt < 4; ++nt)
        acc[mt][nt] = __builtin_amdgcn_mfma_f32_16x16x32_bf16(
            bfr[nt], af[mt], acc[mt][nt], 0, 0, 0);
  }

  // ---- register epilogue + direct dual NT stores ----
  // acc[mt][nt][r] = G[i = i0+wr+mt*16+l16][j = j0+wc+nt*16+quad*4+r]
  const long baseF =
      (long)b * T_DIM * T_DIM + (long)(i0 + wr + l16) * T_DIM + j0 + wc + quad * 4;
  #pragma unroll
  for (int mt = 0; mt < 4; ++mt) {
    const float hi = hA[mt], vi = vA[mt];
    #pragma unroll
    for (int nt = 0; nt < 4; ++nt) {
      const f32x4 c = acc[mt][nt];
      f32x4 val;
      #pragma unroll
      for (int r = 0; r < 4; ++r)
        val[r] = __expf(c[r] - hi - hB[nt][r]) * vi * vB[nt][r];
      f32x4 yv = val;
      // diagonal: i == j possible only when wr==wc && mt==nt && quad==l16>>2
      if (diagblk && wr == wc && mt == nt && quad == (l16 >> 2)) {
        const int rd = l16 & 3;
        val[rd] += JITTER_F;
        yv[rd] += JITTER_F + nA[mt];
      }
      const long off = baseF + (long)(mt * 16) * T_DIM + nt * 16;
      __builtin_nontemporal_store(val, (f32x4*)(f_cov + off));
      __builtin_nontemporal_store(yv, (f32x4*)(y_cov + off));
    }
  }
}

extern "C" void kernel_launch(void* const* d_in, const int* in_sizes, int n_in,
                              void* d_out, int out_size, void* d_ws, size_t ws_size,
                              hipStream_t stream) {
  const float* in = (const float*)d_in[0];
  float* out = (float*)d_out;
  float* mean_out = out;                              // 16384
  float* f_cov = out + (long)B_DIM * T_DIM;           // 4*4096*4096
  float* y_cov = f_cov + (long)B_DIM * T_DIM * T_DIM; // 4*4096*4096

  char* ws = (char*)d_ws;
  bf16_t* Zb = (bf16_t*)ws;                                    // 4 MB
  float* h = (float*)(ws + (size_t)B_DIM * T_DIM * 128 * 2);   // 64 KB
  float* v = h + B_DIM * T_DIM;                                // 64 KB
  float* noise = v + B_DIM * T_DIM;                            // 64 KB

  prep_kernel<<<(B_DIM * T_DIM) / 4, 256, 0, stream>>>(in, mean_out, Zb, h, v, noise);

  dim3 grid(T_DIM / 128, T_DIM / 128, B_DIM);
  cov_kernel<<<grid, 256, 0, stream>>>(Zb, h, v, noise, f_cov, y_cov);
}

// Round 2
// 531.805 us; speedup vs baseline: 1.1001x; 1.1001x over previous
//
#include <hip/hip_runtime.h>

#define T_DIM 4096
#define B_DIM 4
#define NF 131
#define INV_SQRT_D 0.08838834764831845f
#define JITTER_F 1e-6f
#define SSTRIDE 68  // per-wave fp32 staging stride: 17 x 16B (odd) -> conflict-free b128

typedef __bf16 bf16_t;
typedef bf16_t bf16x8 __attribute__((ext_vector_type(8)));
typedef bf16_t bf16x2 __attribute__((ext_vector_type(2)));
typedef float f32x4 __attribute__((ext_vector_type(4)));

// Kernel 1: per-row precompute.
__global__ __launch_bounds__(256) void prep_kernel(
    const float* __restrict__ in, float* __restrict__ mean_out,
    bf16_t* __restrict__ Zb, float* __restrict__ h,
    float* __restrict__ v, float* __restrict__ noise) {
  const int row = blockIdx.x * 4 + (threadIdx.x >> 6);
  const int lane = threadIdx.x & 63;
  const float* x = in + (long)row * NF;
  float z0 = x[1 + lane * 2] * INV_SQRT_D;
  float z1 = x[2 + lane * 2] * INV_SQRT_D;
  bf16x2 p;
  p.x = (bf16_t)z0;
  p.y = (bf16_t)z1;
  *(bf16x2*)(Zb + (long)row * 128 + lane * 2) = p;
  float s = z0 * z0 + z1 * z1;
  #pragma unroll
  for (int m = 32; m > 0; m >>= 1) s += __shfl_down(s, m);
  if (lane == 0) {
    h[row] = 0.5f * s;
    mean_out[row] = x[0];
    v[row] = x[129];
    float t = x[130];
    noise[row] = (t > 15.0f) ? t : log1pf(__expf(t));
  }
}

// Kernel 2: 128x128 tile per block, barrier-free.
// - Swapped-operand MFMA (mfma(B,A)): lane holds 4 consecutive COLUMNS at one
//   row -> register exp-epilogue, no full-tile fp32 LDS round trip.
// - Fragments loaded direct from L1/L2 (Zb = 4 MB, cache-resident).
// - Store granularity fix vs round 1: per-wave LDS transpose staging
//   (16x68 f32 x {f,y}, 8.5 KB/wave, no __syncthreads -- per-wave DS order).
//   Readout: each NT store instruction covers 4 rows x 256 B contiguous
//   (full 128 B lines), restoring fill-kernel-class write efficiency.
__global__ __launch_bounds__(256) void cov_kernel(
    const bf16_t* __restrict__ Zb, const float* __restrict__ h,
    const float* __restrict__ v, const float* __restrict__ noise,
    float* __restrict__ f_cov, float* __restrict__ y_cov) {
  __shared__ __align__(16) float stage[4][2][16 * SSTRIDE];  // 34,816 B

  const int jt = blockIdx.x, it = blockIdx.y, b = blockIdx.z;
  const int i0 = it * 128, j0 = jt * 128;
  const int tid = threadIdx.x;
  const int wave = tid >> 6, lane = tid & 63;
  const int wr = (wave >> 1) * 64, wc = (wave & 1) * 64;
  const int l16 = lane & 15, quad = lane >> 4;

  const int ib = b * T_DIM + i0 + wr + l16;       // row index base (+ mt*16)
  const int jb = b * T_DIM + j0 + wc + quad * 4;  // col index base (+ nt*16)

  const bool diagblk = (it == jt);

  // ---- epilogue params first (L2-hot, early in vmcnt FIFO) ----
  float hA[4], vA[4], nA[4];
  f32x4 hB[4], vB[4];
  #pragma unroll
  for (int mt = 0; mt < 4; ++mt) {
    hA[mt] = h[ib + mt * 16];
    vA[mt] = v[ib + mt * 16];
    nA[mt] = diagblk ? noise[ib + mt * 16] : 0.0f;
  }
  #pragma unroll
  for (int nt = 0; nt < 4; ++nt) {
    hB[nt] = *(const f32x4*)(h + jb + nt * 16);
    vB[nt] = *(const f32x4*)(v + jb + nt * 16);
  }

  // ---- gram via MFMA, fragments direct from cache ----
  const bf16_t* Arow = Zb + ((long)ib << 7);                          // i rows
  const bf16_t* Brow = Zb + ((long)(b * T_DIM + j0 + wc + l16) << 7); // j rows

  f32x4 acc[4][4];
  #pragma unroll
  for (int mt = 0; mt < 4; ++mt)
    #pragma unroll
    for (int nt = 0; nt < 4; ++nt)
      acc[mt][nt] = (f32x4){0.f, 0.f, 0.f, 0.f};

  #pragma unroll
  for (int ks = 0; ks < 4; ++ks) {
    const int ko = ks * 32 + quad * 8;
    bf16x8 af[4], bfr[4];
    #pragma unroll
    for (int mt = 0; mt < 4; ++mt)
      af[mt] = *(const bf16x8*)(Arow + mt * 2048 + ko);
    #pragma unroll
    for (int nt = 0; nt < 4; ++nt)
      bfr[nt] = *(const bf16x8*)(Brow + nt * 2048 + ko);
    #pragma unroll
    for (int mt = 0; mt < 4; ++mt)
      #pragma unroll
      for (int nt = 0; nt < 4; ++nt)
        acc[mt][nt] = __builtin_amdgcn_mfma_f32_16x16x32_bf16(
            bfr[nt], af[mt], acc[mt][nt], 0, 0, 0);
  }

  // ---- register epilogue -> per-wave LDS transpose -> full-line NT stores ----
  float* fb = stage[wave][0];
  float* yb = stage[wave][1];
  const int rl = lane >> 4, c16 = lane & 15;
  const long baseO =
      (long)b * T_DIM * T_DIM + (long)(i0 + wr) * T_DIM + j0 + wc;

  #pragma unroll
  for (int mt = 0; mt < 4; ++mt) {
    const float hi = hA[mt], vi = vA[mt];
    #pragma unroll
    for (int nt = 0; nt < 4; ++nt) {
      const f32x4 c = acc[mt][nt];
      f32x4 val;
      #pragma unroll
      for (int r = 0; r < 4; ++r)
        val[r] = __expf(c[r] - hi - hB[nt][r]) * vi * vB[nt][r];
      f32x4 yv = val;
      // diagonal: i == j only when wr==wc && mt==nt && quad==l16>>2
      if (diagblk && wr == wc && mt == nt && quad == (l16 >> 2)) {
        const int rd = l16 & 3;
        val[rd] += JITTER_F;
        yv[rd] += JITTER_F + nA[mt];
      }
      const int a = l16 * SSTRIDE + nt * 16 + quad * 4;
      *(f32x4*)(fb + a) = val;
      *(f32x4*)(yb + a) = yv;
    }
    // Per-wave readout of this 16x64 slab: row-major, 4 rows x 256 B per instr.
    #pragma unroll
    for (int k = 0; k < 4; ++k) {
      const int rloc = k * 4 + rl;
      const int a2 = rloc * SSTRIDE + c16 * 4;
      const f32x4 fv = *(const f32x4*)(fb + a2);
      const f32x4 yv2 = *(const f32x4*)(yb + a2);
      const long off = baseO + (long)(mt * 16 + rloc) * T_DIM + c16 * 4;
      __builtin_nontemporal_store(fv, (f32x4*)(f_cov + off));
      __builtin_nontemporal_store(yv2, (f32x4*)(y_cov + off));
    }
  }
}

extern "C" void kernel_launch(void* const* d_in, const int* in_sizes, int n_in,
                              void* d_out, int out_size, void* d_ws, size_t ws_size,
                              hipStream_t stream) {
  const float* in = (const float*)d_in[0];
  float* out = (float*)d_out;
  float* mean_out = out;                              // 16384
  float* f_cov = out + (long)B_DIM * T_DIM;           // 4*4096*4096
  float* y_cov = f_cov + (long)B_DIM * T_DIM * T_DIM; // 4*4096*4096

  char* ws = (char*)d_ws;
  bf16_t* Zb = (bf16_t*)ws;                                    // 4 MB
  float* h = (float*)(ws + (size_t)B_DIM * T_DIM * 128 * 2);   // 64 KB
  float* v = h + B_DIM * T_DIM;                                // 64 KB
  float* noise = v + B_DIM * T_DIM;                            // 64 KB

  prep_kernel<<<(B_DIM * T_DIM) / 4, 256, 0, stream>>>(in, mean_out, Zb, h, v, noise);

  dim3 grid(T_DIM / 128, T_DIM / 128, B_DIM);
  cov_kernel<<<grid, 256, 0, stream>>>(Zb, h, v, noise, f_cov, y_cov);
}